// Round 2
// baseline (504.363 us; speedup 1.0000x reference)
//
#include <hip/hip_runtime.h>

// stepSSM v3: 4 lanes per row, 2 rows per thread.
// - Cross-lane reductions via DPP quad_perm (v_mov_b32 dpp, 2cy VALU) instead of
//   __shfl_xor's ds_bpermute (LDS pipe + lgkmcnt latency): partners are lane^1/lane^2,
//   strictly within a quad.
// - All 8 state loads (4 layers x 2 rows) issued before the layer loop: 8 outstanding
//   16B loads/lane for memory-level parallelism.
// - Weight fragments (a/b/C) shared between the thread's two rows: LDS read traffic halved.
// - nt dropped on loads (allow opportunistic L3 hits), kept on stores (never re-read).

constexpr float NEG_SLOPE = 0.125f;

typedef float fv4 __attribute__((ext_vector_type(4)));

template<int CTRL>
__device__ __forceinline__ float qperm(float v) {
    // quad_perm DPP move; all lanes in a quad are active together (guards exit whole quads).
    return __int_as_float(__builtin_amdgcn_mov_dpp(__float_as_int(v), CTRL, 0xF, 0xF, true));
}

__global__ __launch_bounds__(256) void ssm_fused(
    const float* __restrict__ x,
    const float* __restrict__ states,
    const float* __restrict__ fc1_w,
    const float* __restrict__ fc1_b,
    const float* __restrict__ fc_w,
    const float* __restrict__ fc_b,
    const float* __restrict__ A,
    const float* __restrict__ Bm,
    const float* __restrict__ Cm,
    const float* __restrict__ Dm,
    float* __restrict__ out_h,
    float* __restrict__ out_states,
    int B)
{
    __shared__ __align__(16) float w[240];
    const int t = threadIdx.x;
    if (t < 240) {
        float v;
        if (t < 8)        v = fc1_w[t];
        else if (t < 10)  v = fc1_b[t - 8];
        else if (t < 30)  v = fc_w[t - 10];
        else if (t < 40)  v = fc_b[t - 30];
        else if (t < 104) v = A[t - 40];
        else if (t < 168) v = Bm[t - 104];
        else if (t < 232) v = Cm[t - 168];
        else              v = Dm[t - 232];
        w[t] = v;
    }
    __syncthreads();

    const int g = blockIdx.x * 256 + t;
    const int q = g >> 2;              // quad id: handles rows q and q + r0cnt
    const int c = g & 3;               // chunk: hh = c>>1, f = 2*(c&1)+{0,1}
    const int r0cnt = (B + 1) >> 1;
    if (q >= r0cnt) return;

    const int n0 = q;
    const int n1 = q + r0cnt;
    const bool has1 = (n1 < B);

    const int B16 = B * 16;            // floats per layer plane (fits int: 4*B*16 < 2^27)
    const int c4  = c * 4;
    const int f0  = n0 * 16 + c4;
    const int f1  = n1 * 16 + c4;

    // Issue all state loads up front (8 outstanding 16B loads/lane).
    fv4 s0[4], s1[4];
#pragma unroll
    for (int i = 0; i < 4; ++i) {
        s0[i] = *(const fv4*)(states + f0 + i * B16);
        if (has1) s1[i] = *(const fv4*)(states + f1 + i * B16);
    }

    const float4 xv0 = ((const float4*)x)[n0];
    float hA0 = w[8] + xv0.x * w[0] + xv0.y * w[1] + xv0.z * w[2] + xv0.w * w[3];
    float hA1 = w[9] + xv0.x * w[4] + xv0.y * w[5] + xv0.z * w[6] + xv0.w * w[7];
    float hB0 = 0.f, hB1 = 0.f;
    if (has1) {
        const float4 xv1 = ((const float4*)x)[n1];
        hB0 = w[8] + xv1.x * w[0] + xv1.y * w[1] + xv1.z * w[2] + xv1.w * w[3];
        hB1 = w[9] + xv1.x * w[4] + xv1.y * w[5] + xv1.z * w[6] + xv1.w * w[7];
    }

    const float* wA  = w + 40;   // [4][2][4][2]
    const float* wB  = w + 104;
    const float* wC  = w + 168;
    const float* wD  = w + 232;  // [4][2]
    const float* wfc = w + 10;   // [5][2][2]
    const float* wfb = w + 30;   // [5][2]
    const bool hi = (c & 2) != 0;

#pragma unroll
    for (int i = 0; i < 4; ++i) {
        // Weight fragments: shared by both rows of this thread.
        const fv4 a  = *(const fv4*)(wA + i * 16 + c4);   // (Ar0,Ai0,Ar1,Ai1)
        const fv4 b  = *(const fv4*)(wB + i * 16 + c4);
        const fv4 cw = *(const fv4*)(wC + i * 16 + c4);
        const float d0  = wD[i * 2 + 0], d1  = wD[i * 2 + 1];
        const float w00 = wfc[i * 4 + 0], w01 = wfc[i * 4 + 1];
        const float w10 = wfc[i * 4 + 2], w11 = wfc[i * 4 + 3];
        const float fb0 = wfb[i * 2 + 0], fb1 = wfb[i * 2 + 1];

        // ---- row 0 ----
        {
            const fv4 s = s0[i];
            const float u = hi ? hA1 : hA0;
            const float nr0 = a.x * s.x - a.y * s.y + b.x * u;
            const float ni0 = a.x * s.y + a.y * s.x + b.y * u;
            const float nr1 = a.z * s.z - a.w * s.w + b.z * u;
            const float ni1 = a.z * s.w + a.w * s.z + b.w * u;
            float part = cw.x * nr0 - cw.y * ni0 + cw.z * nr1 - cw.w * ni1;
            part += qperm<0xB1>(part);              // + lane^1: sum over 4 f within own hh
            const float other = qperm<0x4E>(part);  // lane^2: the other hh's sum
            const float acc0 = hi ? other : part;
            const float acc1 = hi ? part  : other;
            float y0 = 2.f * acc0 + hA0 * d0;
            float y1 = 2.f * acc1 + hA1 * d1;
            y0 = (y0 >= 0.f) ? y0 : NEG_SLOPE * y0;
            y1 = (y1 >= 0.f) ? y1 : NEG_SLOPE * y1;
            hA0 = fb0 + w00 * y0 + w01 * y1;
            hA1 = fb1 + w10 * y0 + w11 * y1;
            fv4 nsv; nsv.x = nr0; nsv.y = ni0; nsv.z = nr1; nsv.w = ni1;
            __builtin_nontemporal_store(nsv, (fv4*)(out_states + f0 + i * B16));
        }
        // ---- row 1 ----
        if (has1) {
            const fv4 s = s1[i];
            const float u = hi ? hB1 : hB0;
            const float nr0 = a.x * s.x - a.y * s.y + b.x * u;
            const float ni0 = a.x * s.y + a.y * s.x + b.y * u;
            const float nr1 = a.z * s.z - a.w * s.w + b.z * u;
            const float ni1 = a.z * s.w + a.w * s.z + b.w * u;
            float part = cw.x * nr0 - cw.y * ni0 + cw.z * nr1 - cw.w * ni1;
            part += qperm<0xB1>(part);
            const float other = qperm<0x4E>(part);
            const float acc0 = hi ? other : part;
            const float acc1 = hi ? part  : other;
            float y0 = 2.f * acc0 + hB0 * d0;
            float y1 = 2.f * acc1 + hB1 * d1;
            y0 = (y0 >= 0.f) ? y0 : NEG_SLOPE * y0;
            y1 = (y1 >= 0.f) ? y1 : NEG_SLOPE * y1;
            hB0 = fb0 + w00 * y0 + w01 * y1;
            hB1 = fb1 + w10 * y0 + w11 * y1;
            fv4 nsv; nsv.x = nr0; nsv.y = ni0; nsv.z = nr1; nsv.w = ni1;
            __builtin_nontemporal_store(nsv, (fv4*)(out_states + f1 + i * B16));
        }
    }

    // fc10 — one lane per quad writes 8B per row.
    if (c == 0) {
        float2* o2 = (float2*)out_h;
        o2[n0] = make_float2(wfb[8] + wfc[16] * hA0 + wfc[17] * hA1,
                             wfb[9] + wfc[18] * hA0 + wfc[19] * hA1);
        if (has1)
            o2[n1] = make_float2(wfb[8] + wfc[16] * hB0 + wfc[17] * hB1,
                                 wfb[9] + wfc[18] * hB0 + wfc[19] * hB1);
    }
}

extern "C" void kernel_launch(void* const* d_in, const int* in_sizes, int n_in,
                              void* d_out, int out_size, void* d_ws, size_t ws_size,
                              hipStream_t stream) {
    const float* x      = (const float*)d_in[0];
    const float* states = (const float*)d_in[1];
    const float* fc1_w  = (const float*)d_in[2];
    const float* fc1_b  = (const float*)d_in[3];
    const float* fc_w   = (const float*)d_in[4];
    const float* fc_b   = (const float*)d_in[5];
    const float* A      = (const float*)d_in[6];
    const float* Bm     = (const float*)d_in[7];
    const float* Cm     = (const float*)d_in[8];
    const float* Dm     = (const float*)d_in[9];
    const int B = in_sizes[0] / 4;   // same convention as the verified v1/v2 kernels

    float* out_h      = (float*)d_out;
    float* out_states = (float*)d_out + (size_t)2 * (size_t)B;

    const long long r0cnt = ((long long)B + 1) / 2;
    const long long threads = 4LL * r0cnt;     // 4 lanes x (ceil(B/2)) quads
    dim3 grid((unsigned)((threads + 255) / 256)), block(256);
    hipLaunchKernelGGL(ssm_fused, grid, block, 0, stream,
                       x, states, fc1_w, fc1_b, fc_w, fc_b, A, Bm, Cm, Dm,
                       out_h, out_states, B);
}

// Round 3
// 484.108 us; speedup vs baseline: 1.0418x; 1.0418x over previous
//
#include <hip/hip_runtime.h>

// stepSSM v4 = v2 structure + v3's verified-good pieces.
// - 1 row per thread, 4 lanes per row (65536 waves — v3's 2-row split halved TLP and
//   regressed 125->185 us; reverted).
// - Cross-lane reduction via DPP quad_perm (2cy VALU) instead of ds_bpermute shuffles.
// - PLAIN loads on states: v3's FETCH_SIZE=139MB (vs 272MB stream) proved plain loads
//   retain reads in the 256MiB L3 across timed iterations; v2's nontemporal loads
//   bypassed allocation and paid full HBM fetch. ~21 us of HBM time saved.
// - Nontemporal stores kept: output is never re-read; keeps write stream from evicting
//   the read stream's L3 lines.
// - All 4 layer-state loads issued before the layer loop (4 outstanding 16B loads/lane).

constexpr float NEG_SLOPE = 0.125f;

typedef float fv4 __attribute__((ext_vector_type(4)));

template<int CTRL>
__device__ __forceinline__ float qperm(float v) {
    // quad_perm DPP move; partners are within the quad, all quad lanes active together.
    return __int_as_float(__builtin_amdgcn_mov_dpp(__float_as_int(v), CTRL, 0xF, 0xF, true));
}

__global__ __launch_bounds__(256) void ssm_fused(
    const float* __restrict__ x,
    const float* __restrict__ states,
    const float* __restrict__ fc1_w,
    const float* __restrict__ fc1_b,
    const float* __restrict__ fc_w,
    const float* __restrict__ fc_b,
    const float* __restrict__ A,
    const float* __restrict__ Bm,
    const float* __restrict__ Cm,
    const float* __restrict__ Dm,
    float* __restrict__ out_h,
    float* __restrict__ out_states,
    int B)
{
    __shared__ __align__(16) float w[240];
    const int t = threadIdx.x;
    if (t < 240) {
        float v;
        if (t < 8)        v = fc1_w[t];
        else if (t < 10)  v = fc1_b[t - 8];
        else if (t < 30)  v = fc_w[t - 10];
        else if (t < 40)  v = fc_b[t - 30];
        else if (t < 104) v = A[t - 40];
        else if (t < 168) v = Bm[t - 104];
        else if (t < 232) v = Cm[t - 168];
        else              v = Dm[t - 232];
        w[t] = v;
    }
    __syncthreads();

    const int g = blockIdx.x * 256 + t;
    const int n = g >> 2;              // row
    const int c = g & 3;               // chunk: hh = c>>1, f = 2*(c&1)+{0,1}
    if (n >= B) return;

    const int B16 = B * 16;            // floats per layer plane (4*B*16 < 2^27, fits int)
    const int f0  = n * 16 + c * 4;

    // Issue all 4 state loads up front (plain loads -> L3 allocation & reuse).
    fv4 s[4];
#pragma unroll
    for (int i = 0; i < 4; ++i) s[i] = *(const fv4*)(states + f0 + i * B16);

    const float4 xv = ((const float4*)x)[n];
    float h0 = w[8] + xv.x * w[0] + xv.y * w[1] + xv.z * w[2] + xv.w * w[3];
    float h1 = w[9] + xv.x * w[4] + xv.y * w[5] + xv.z * w[6] + xv.w * w[7];

    const float* wA  = w + 40;   // [4][2][4][2]
    const float* wB  = w + 104;
    const float* wC  = w + 168;
    const float* wD  = w + 232;  // [4][2]
    const float* wfc = w + 10;   // [5][2][2]
    const float* wfb = w + 30;   // [5][2]
    const bool hi = (c & 2) != 0;

#pragma unroll
    for (int i = 0; i < 4; ++i) {
        const fv4 a  = *(const fv4*)(wA + i * 16 + c * 4);   // (Ar0,Ai0,Ar1,Ai1)
        const fv4 b  = *(const fv4*)(wB + i * 16 + c * 4);
        const fv4 cw = *(const fv4*)(wC + i * 16 + c * 4);

        const fv4 sv = s[i];
        const float u = hi ? h1 : h0;
        const float nr0 = a.x * sv.x - a.y * sv.y + b.x * u;
        const float ni0 = a.x * sv.y + a.y * sv.x + b.y * u;
        const float nr1 = a.z * sv.z - a.w * sv.w + b.z * u;
        const float ni1 = a.z * sv.w + a.w * sv.z + b.w * u;

        float part = cw.x * nr0 - cw.y * ni0 + cw.z * nr1 - cw.w * ni1;
        part += qperm<0xB1>(part);              // + lane^1: full sum over f within own hh
        const float other = qperm<0x4E>(part);  // lane^2: the other hh's sum
        const float acc0 = hi ? other : part;
        const float acc1 = hi ? part  : other;

        float y0 = 2.f * acc0 + h0 * wD[i * 2 + 0];
        float y1 = 2.f * acc1 + h1 * wD[i * 2 + 1];
        y0 = (y0 >= 0.f) ? y0 : NEG_SLOPE * y0;
        y1 = (y1 >= 0.f) ? y1 : NEG_SLOPE * y1;
        const float nh0 = wfb[i * 2 + 0] + wfc[i * 4 + 0] * y0 + wfc[i * 4 + 1] * y1;
        const float nh1 = wfb[i * 2 + 1] + wfc[i * 4 + 2] * y0 + wfc[i * 4 + 3] * y1;
        h0 = nh0; h1 = nh1;

        fv4 nsv; nsv.x = nr0; nsv.y = ni0; nsv.z = nr1; nsv.w = ni1;
        __builtin_nontemporal_store(nsv, (fv4*)(out_states + f0 + i * B16));
    }

    // fc10 — one lane per quad writes the 8B result.
    if (c == 0) {
        const float o0 = wfb[8] + wfc[16] * h0 + wfc[17] * h1;
        const float o1 = wfb[9] + wfc[18] * h0 + wfc[19] * h1;
        ((float2*)out_h)[n] = make_float2(o0, o1);
    }
}

extern "C" void kernel_launch(void* const* d_in, const int* in_sizes, int n_in,
                              void* d_out, int out_size, void* d_ws, size_t ws_size,
                              hipStream_t stream) {
    const float* x      = (const float*)d_in[0];
    const float* states = (const float*)d_in[1];
    const float* fc1_w  = (const float*)d_in[2];
    const float* fc1_b  = (const float*)d_in[3];
    const float* fc_w   = (const float*)d_in[4];
    const float* fc_b   = (const float*)d_in[5];
    const float* A      = (const float*)d_in[6];
    const float* Bm     = (const float*)d_in[7];
    const float* Cm     = (const float*)d_in[8];
    const float* Dm     = (const float*)d_in[9];
    const int B = in_sizes[0] / 4;   // same convention as verified v1/v2 kernels

    float* out_h      = (float*)d_out;
    float* out_states = (float*)d_out + (size_t)2 * (size_t)B;

    const long long threads = 4LL * (long long)B;   // 4 lanes per row
    dim3 grid((unsigned)((threads + 255) / 256)), block(256);
    hipLaunchKernelGGL(ssm_fused, grid, block, 0, stream,
                       x, states, fc1_w, fc1_b, fc_w, fc_b, A, Bm, Cm, Dm,
                       out_h, out_states, B);
}